// Round 9
// baseline (792.736 us; speedup 1.0000x reference)
//
#include <hip/hip_runtime.h>

#define N_ROWS 16384
#define OBS    1024
#define HID    2048
#define LAT    256
#define VOCAB  8192
#define HQ     4
#define LN_EPS 1e-5f

typedef unsigned short u16;
typedef unsigned long long u64;
typedef __bf16 bf16x8 __attribute__((ext_vector_type(8)));
typedef float  f32x4  __attribute__((ext_vector_type(4)));

static __device__ __forceinline__ unsigned int float_to_ordered(float f) {
    unsigned int u = __float_as_uint(f);
    return (u & 0x80000000u) ? ~u : (u | 0x80000000u);
}
// fp32 -> bf16 round-to-nearest-even
static __device__ __forceinline__ u16 f2bf(float f) {
    unsigned int u = __float_as_uint(f);
    unsigned int r = u + 0x7FFFu + ((u >> 16) & 1u);
    return (u16)(r >> 16);
}
static __device__ __forceinline__ float bf2f(u16 u) {
    return __uint_as_float((unsigned int)u << 16);
}

#define GL2LDS(gp, lp) __builtin_amdgcn_global_load_lds( \
    (const __attribute__((address_space(1))) void*)(gp), \
    (__attribute__((address_space(3))) void*)(lp), 16, 0, 0)

// ---------------------------------------------------------------------------
// bf16 MFMA GEMM, 128x128 tile, C = A @ B^T + bias. (verified rounds 3-6)
// EPI 0: store bf16 C.  1: relu + store bf16 C.  3: fused loss, no store.
// ---------------------------------------------------------------------------
template<int EPI>
__global__ __launch_bounds__(256, 4) void mfma_gemm_k(
    const u16* __restrict__ Abf, const u16* __restrict__ Bbf,
    const float* __restrict__ bias,
    u16* __restrict__ Cbf,
    const float* __restrict__ X, double* __restrict__ lacc,
    int K, int Nd)
{
    __shared__ u16 As[128 * 64];
    __shared__ u16 Bs[128 * 64];

    const int tid  = threadIdx.x;
    const int wv   = tid >> 6, lane = tid & 63;
    const int wm   = wv & 1,   wn   = wv >> 1;
    const int m_   = lane & 15, g   = lane >> 4;
    const int m0   = blockIdx.x * 128;
    const int n0   = blockIdx.y * 128;

    f32x4 acc[4][4];
#pragma unroll
    for (int i = 0; i < 4; ++i)
#pragma unroll
        for (int j = 0; j < 4; ++j)
            acc[i][j] = f32x4{0.f, 0.f, 0.f, 0.f};

    const u16* Ablk = Abf + (size_t)m0 * K;
    const u16* Bblk = Bbf + (size_t)n0 * K;

    for (int k0 = 0; k0 < K; k0 += 64) {
#pragma unroll
        for (int c = 0; c < 4; ++c) {
            const int ci = (wv * 4 + c) * 64 + lane;
            const int r  = ci >> 3;
            const int cc = ci & 7;
            const int kc = (cc ^ (r & 7)) << 3;
            GL2LDS(Ablk + (size_t)r * K + k0 + kc, As + (wv * 4 + c) * 512);
            GL2LDS(Bblk + (size_t)r * K + k0 + kc, Bs + (wv * 4 + c) * 512);
        }
        __syncthreads();
#pragma unroll
        for (int ks = 0; ks < 2; ++ks) {
            const int ccw = ks * 4 + g;
            const int sw  = (ccw ^ (m_ & 7)) << 3;
            bf16x8 af[4], bfr[4];
#pragma unroll
            for (int t = 0; t < 4; ++t) {
                af[t]  = *(const bf16x8*)&As[(wm * 64 + t * 16 + m_) * 64 + sw];
                bfr[t] = *(const bf16x8*)&Bs[(wn * 64 + t * 16 + m_) * 64 + sw];
            }
#pragma unroll
            for (int mi = 0; mi < 4; ++mi)
#pragma unroll
                for (int ni = 0; ni < 4; ++ni)
                    acc[mi][ni] = __builtin_amdgcn_mfma_f32_16x16x32_bf16(
                        af[mi], bfr[ni], acc[mi][ni], 0, 0, 0);
        }
        __syncthreads();
    }

    float bs[4];
#pragma unroll
    for (int ni = 0; ni < 4; ++ni) bs[ni] = bias[n0 + wn * 64 + ni * 16 + m_];

    if constexpr (EPI == 3) {
        float lsum = 0.f;
#pragma unroll
        for (int mi = 0; mi < 4; ++mi)
#pragma unroll
            for (int j = 0; j < 4; ++j) {
                const int row = m0 + wm * 64 + mi * 16 + g * 4 + j;
#pragma unroll
                for (int ni = 0; ni < 4; ++ni) {
                    const int col = n0 + wn * 64 + ni * 16 + m_;
                    float r = acc[mi][ni][j] + bs[ni] - X[(size_t)row * Nd + col];
                    lsum = fmaf(r, r, lsum);
                }
            }
#pragma unroll
        for (int off = 32; off >= 1; off >>= 1) lsum += __shfl_xor(lsum, off);
        __shared__ float red[4];
        if (lane == 0) red[wv] = lsum;
        __syncthreads();
        if (tid == 0)
            atomicAdd(lacc, (double)(red[0] + red[1] + red[2] + red[3]));
    } else {
#pragma unroll
        for (int mi = 0; mi < 4; ++mi)
#pragma unroll
            for (int j = 0; j < 4; ++j) {
                const int row = m0 + wm * 64 + mi * 16 + g * 4 + j;
#pragma unroll
                for (int ni = 0; ni < 4; ++ni) {
                    const int col = n0 + wn * 64 + ni * 16 + m_;
                    float v = acc[mi][ni][j] + bs[ni];
                    if constexpr (EPI == 1) v = fmaxf(v, 0.f);
                    Cbf[(size_t)row * Nd + col] = f2bf(v);
                }
            }
    }
}

// ---------------------------------------------------------------------------
// GEMM2 dedicated kernel: 64x64 tile.  latent = h @ w2T^T + b2.
// (resid store dropped round-8; vq level-0 reads latent.)
// ---------------------------------------------------------------------------
__global__ __launch_bounds__(256, 4) void gemm2_k(
    const u16* __restrict__ Abf, const u16* __restrict__ Bbf,
    const float* __restrict__ bias,
    float* __restrict__ lat, u16* __restrict__ rbf)
{
    __shared__ u16 As[64 * 64];
    __shared__ u16 Bs[64 * 64];

    const int tid = threadIdx.x;
    const int wv  = tid >> 6, lane = tid & 63;
    const int wm  = wv & 1,   wn   = wv >> 1;
    const int m_  = lane & 15, g   = lane >> 4;
    const int m0  = blockIdx.x * 64;
    const int n0  = blockIdx.y * 64;

    f32x4 acc[2][2];
#pragma unroll
    for (int i = 0; i < 2; ++i)
#pragma unroll
        for (int j = 0; j < 2; ++j)
            acc[i][j] = f32x4{0.f, 0.f, 0.f, 0.f};

    const u16* Ablk = Abf + (size_t)m0 * HID;
    const u16* Bblk = Bbf + (size_t)n0 * HID;

    for (int k0 = 0; k0 < HID; k0 += 64) {
#pragma unroll
        for (int c = 0; c < 2; ++c) {
            const int ci = (wv * 2 + c) * 64 + lane;
            const int r  = ci >> 3;
            const int cc = ci & 7;
            const int kc = (cc ^ (r & 7)) << 3;
            GL2LDS(Ablk + (size_t)r * HID + k0 + kc, As + (wv * 2 + c) * 512);
            GL2LDS(Bblk + (size_t)r * HID + k0 + kc, Bs + (wv * 2 + c) * 512);
        }
        __syncthreads();
#pragma unroll
        for (int ks = 0; ks < 2; ++ks) {
            const int ccw = ks * 4 + g;
            const int sw  = (ccw ^ (m_ & 7)) << 3;
            bf16x8 af[2], bfr[2];
#pragma unroll
            for (int t = 0; t < 2; ++t) {
                af[t]  = *(const bf16x8*)&As[(wm * 32 + t * 16 + m_) * 64 + sw];
                bfr[t] = *(const bf16x8*)&Bs[(wn * 32 + t * 16 + m_) * 64 + sw];
            }
#pragma unroll
            for (int mi = 0; mi < 2; ++mi)
#pragma unroll
                for (int ni = 0; ni < 2; ++ni)
                    acc[mi][ni] = __builtin_amdgcn_mfma_f32_16x16x32_bf16(
                        af[mi], bfr[ni], acc[mi][ni], 0, 0, 0);
        }
        __syncthreads();
    }

#pragma unroll
    for (int mi = 0; mi < 2; ++mi)
#pragma unroll
        for (int j = 0; j < 4; ++j) {
            const int row = m0 + wm * 32 + mi * 16 + g * 4 + j;
#pragma unroll
            for (int ni = 0; ni < 2; ++ni) {
                const int col = n0 + wn * 32 + ni * 16 + m_;
                float v = acc[mi][ni][j] + bias[col];
                lat[(size_t)row * LAT + col] = v;
                rbf[(size_t)row * LAT + col] = f2bf(v);
            }
        }
}

// ---------------------------------------------------------------------------
// Prep kernel: 4 weight transposes (blocks 0..5119) + x fp32->bf16
// (blocks 5120..21503) in ONE launch.
// ---------------------------------------------------------------------------
__global__ __launch_bounds__(256) void prep_k(
    const float* __restrict__ W0, u16* __restrict__ T0,   // enc_w1 1024x2048
    const float* __restrict__ W1, u16* __restrict__ T1,   // enc_w2 2048x256
    const float* __restrict__ W2, u16* __restrict__ T2,   // dec_w1 256x2048
    const float* __restrict__ W3, u16* __restrict__ T3,   // dec_w2 2048x1024
    const float* __restrict__ x, u16* __restrict__ xbf)
{
    __shared__ u16 t[32][33];
    const int bid = blockIdx.x;
    if (bid >= 5120) {   // f2bf path
        size_t i = ((size_t)(bid - 5120) * 256 + threadIdx.x) * 4;
        float4 v = *(const float4*)(x + i);
        ushort4 o;
        o.x = f2bf(v.x); o.y = f2bf(v.y); o.z = f2bf(v.z); o.w = f2bf(v.w);
        *(ushort4*)(xbf + i) = o;
        return;
    }
    const float* W; u16* T; int K, N, r;
    if (bid < 2048)      { W = W0; T = T0; K = OBS; N = HID; r = bid; }
    else if (bid < 2560) { W = W1; T = T1; K = HID; N = LAT; r = bid - 2048; }
    else if (bid < 3072) { W = W2; T = T2; K = LAT; N = HID; r = bid - 2560; }
    else                 { W = W3; T = T3; K = HID; N = OBS; r = bid - 3072; }
    const int nb = N >> 5;
    const int n0 = (r % nb) * 32, k0 = (r / nb) * 32;
    const int lx = threadIdx.x & 31, ly = threadIdx.x >> 5;
#pragma unroll
    for (int i = 0; i < 4; ++i)
        t[ly + 8 * i][lx] = f2bf(W[(size_t)(k0 + ly + 8 * i) * N + n0 + lx]);
    __syncthreads();
#pragma unroll
    for (int i = 0; i < 4; ++i)
        T[(size_t)(n0 + ly + 8 * i) * K + k0 + lx] = t[lx][ly + 8 * i];
}

// ---------------------------------------------------------------------------
// LayerNorm + ReLU in place on bf16 h (fp32 math), one block per row of 2048.
// ---------------------------------------------------------------------------
__device__ __forceinline__ float block_reduce_bcast(float v, float* scratch) {
#pragma unroll
    for (int off = 32; off >= 1; off >>= 1) v += __shfl_xor(v, off);
    const int tid = threadIdx.x;
    __syncthreads();
    if ((tid & 63) == 0) scratch[tid >> 6] = v;
    __syncthreads();
    return scratch[0] + scratch[1] + scratch[2] + scratch[3];
}

__global__ __launch_bounds__(256) void ln_relu_bf_k(
    u16* __restrict__ h, const float* __restrict__ g, const float* __restrict__ b)
{
    __shared__ float scratch[4];
    const int tid = threadIdx.x;
    u16* hp = h + (size_t)blockIdx.x * HID + tid * 8;

    ushort4 r0 = *(const ushort4*)hp;
    ushort4 r1 = *(const ushort4*)(hp + 4);
    float v[8] = {bf2f(r0.x), bf2f(r0.y), bf2f(r0.z), bf2f(r0.w),
                  bf2f(r1.x), bf2f(r1.y), bf2f(r1.z), bf2f(r1.w)};

    float s = 0.f;
#pragma unroll
    for (int e = 0; e < 8; ++e) s += v[e];
    const float mu = block_reduce_bcast(s, scratch) * (1.f / HID);

    float vs = 0.f;
#pragma unroll
    for (int e = 0; e < 8; ++e) { float d = v[e] - mu; vs = fmaf(d, d, vs); }
    const float var = block_reduce_bcast(vs, scratch) * (1.f / HID);
    const float rs = rsqrtf(var + LN_EPS);

    ushort4 o0, o1;
#pragma unroll
    for (int e = 0; e < 8; ++e) {
        const int col = tid * 8 + e;
        float w = (v[e] - mu) * rs * g[col] + b[col];
        w = fmaxf(w, 0.f);
        u16 bb = f2bf(w);
        if (e < 4) ((u16*)&o0)[e] = bb; else ((u16*)&o1)[e - 4] = bb;
    }
    *(ushort4*)hp = o0;
    *(ushort4*)(hp + 4) = o1;
}

// ---------------------------------------------------------------------------
// Fused codebook pass: exact fp32 norms + bf16(-2E) copy + keys/accs init.
// ---------------------------------------------------------------------------
__global__ __launch_bounds__(256) void enorm_k(
    const float* __restrict__ cb, float* __restrict__ enorm,
    u16* __restrict__ cbb, u64* __restrict__ keys, double* __restrict__ accs)
{
    if (blockIdx.x < 64) keys[blockIdx.x * 256 + threadIdx.x] = ~0ull;
    if (blockIdx.x == 64 && threadIdx.x < 2) accs[threadIdx.x] = 0.0;
    const int row  = blockIdx.x * 4 + (threadIdx.x >> 6);
    const int lane = threadIdx.x & 63;
    const size_t off = (size_t)row * LAT + lane * 4;
    float4 v = *(const float4*)(cb + off);
    ushort4 o;
    o.x = f2bf(-2.f * v.x); o.y = f2bf(-2.f * v.y);
    o.z = f2bf(-2.f * v.z); o.w = f2bf(-2.f * v.w);
    *(ushort4*)(cbb + off) = o;
    float s = v.x * v.x + v.y * v.y + v.z * v.z + v.w * v.w;
#pragma unroll
    for (int off2 = 32; off2 >= 1; off2 >>= 1) s += __shfl_xor(s, off2);
    if (lane == 0) enorm[row] = s;
}

// ---------------------------------------------------------------------------
// Distance + argmin: exact round-2/5 structure (proven 87.0/87.5 us twice):
// 16 phases x 64 cols, 2x32KB double-buffered LDS, plain __syncthreads,
// A-fragments resident (AGPR half of unified file), float fold, enorm
// register prefetch.  Round-9: setprio REMOVED (round-8 A/B: +4.6 us/dispatch
// regression, replicating m190's null-to-negative on lockstep GEMM).
// ---------------------------------------------------------------------------
#define DNT 16

__global__ __launch_bounds__(256, 2) void dist_mfma_k(
    const u16* __restrict__ Abf, const u16* __restrict__ Bneg2,
    const float* __restrict__ enorm, u64* __restrict__ keys)
{
    __shared__ u16 Bs[2][64 * 256];   // 2 x 32 KB double buffer
    __shared__ u64 shk[128][2];

    const int tid  = threadIdx.x;
    const int wv   = tid >> 6, lane = tid & 63;
    const int wm   = wv & 1,   wn   = wv >> 1;
    const int m_   = lane & 15, g   = lane >> 4;
    const int m0   = blockIdx.x * 128;
    const int c0   = blockIdx.y * (64 * DNT);

    // ---- A fragments: direct global -> registers, K=256 resident ----------
    bf16x8 af[4][8];
    {
        const u16* Ablk = Abf + (size_t)m0 * LAT;
#pragma unroll
        for (int mi = 0; mi < 4; ++mi) {
            const u16* rp = Ablk + (size_t)(wm * 64 + mi * 16 + m_) * LAT + g * 8;
#pragma unroll
            for (int kk = 0; kk < 8; ++kk)
                af[mi][kk] = *(const bf16x8*)(rp + kk * 32);
        }
    }

    float bestf[4][4];
    int   besti[4][4];
#pragma unroll
    for (int mi = 0; mi < 4; ++mi)
#pragma unroll
        for (int j4 = 0; j4 < 4; ++j4) {
            bestf[mi][j4] = __int_as_float(0x7f800000);  // +inf
            besti[mi][j4] = 0;
        }

    const u16* Bbase = Bneg2 + (size_t)c0 * LAT;

    // stage B sub-tile j (64 vocab rows x 256 K) into buffer buf
    auto stageB = [&](int j, int buf) {
#pragma unroll
        for (int t = 0; t < 4; ++t)
#pragma unroll
            for (int c = 0; c < 2; ++c) {
                const int idx = (wv * 2 + c) * 64 + lane;
                const int r   = idx >> 3;
                const int cc  = idx & 7;
                const int kc  = (cc ^ (r & 7)) << 3;
                GL2LDS(Bbase + (size_t)(j * 64 + r) * LAT + t * 64 + kc,
                       &Bs[buf][t * 4096 + (wv * 2 + c) * 512]);
            }
    };

    stageB(0, 0);

    // enorm prefetch, one sub-tile ahead
    const int ecol = wn * 32 + m_;
    float enA = enorm[c0 + ecol];
    float enB = enorm[c0 + ecol + 16];

    __syncthreads();

    for (int j = 0; j < DNT; ++j) {
        const int cur = j & 1;
        if (j + 1 < DNT) stageB(j + 1, cur ^ 1);

        float enA_n = 0.f, enB_n = 0.f;
        if (j + 1 < DNT) {
            enA_n = enorm[c0 + (j + 1) * 64 + ecol];
            enB_n = enorm[c0 + (j + 1) * 64 + ecol + 16];
        }

        const int bc = c0 + j * 64 + ecol;
        f32x4 acc[4][2];
#pragma unroll
        for (int mi = 0; mi < 4; ++mi) {
            acc[mi][0] = f32x4{enA, enA, enA, enA};
            acc[mi][1] = f32x4{enB, enB, enB, enB};
        }

        const u16* bsc = &Bs[cur][0];
#pragma unroll
        for (int kc_ = 0; kc_ < 4; ++kc_)
#pragma unroll
            for (int ks = 0; ks < 2; ++ks) {
                const int ccw = ks * 4 + g;
                const int sw  = (ccw ^ (m_ & 7)) << 3;
                bf16x8 b0 = *(const bf16x8*)
                    &bsc[kc_ * 4096 + (wn * 32 + m_) * 64 + sw];
                bf16x8 b1 = *(const bf16x8*)
                    &bsc[kc_ * 4096 + (wn * 32 + 16 + m_) * 64 + sw];
                const int kk = kc_ * 2 + ks;
#pragma unroll
                for (int mi = 0; mi < 4; ++mi) {
                    acc[mi][0] = __builtin_amdgcn_mfma_f32_16x16x32_bf16(
                        af[mi][kk], b0, acc[mi][0], 0, 0, 0);
                    acc[mi][1] = __builtin_amdgcn_mfma_f32_16x16x32_bf16(
                        af[mi][kk], b1, acc[mi][1], 0, 0, 0);
                }
            }

        // cheap fold: float compare + index select, ascending column order
#pragma unroll
        for (int mi = 0; mi < 4; ++mi)
#pragma unroll
            for (int j4 = 0; j4 < 4; ++j4) {
                const float s0 = acc[mi][0][j4];
                const float s1 = acc[mi][1][j4];
                if (s0 < bestf[mi][j4]) { bestf[mi][j4] = s0; besti[mi][j4] = bc; }
                if (s1 < bestf[mi][j4]) { bestf[mi][j4] = s1; besti[mi][j4] = bc + 16; }
            }

        enA = enA_n; enB = enB_n;
        __syncthreads();   // Bs[cur^1] staged complete; Bs[cur] reads done
    }

    // ---- epilogue: pack once, reduce over the 16 m_ lanes, merge wn halves
#pragma unroll
    for (int mi = 0; mi < 4; ++mi)
#pragma unroll
        for (int j4 = 0; j4 < 4; ++j4) {
            u64 b = ((u64)float_to_ordered(bestf[mi][j4]) << 32)
                  | (unsigned)besti[mi][j4];
#pragma unroll
            for (int mask = 1; mask <= 8; mask <<= 1) {
                u64 o = __shfl_xor(b, mask);
                b = o < b ? o : b;
            }
            if (m_ == 0) shk[wm * 64 + mi * 16 + g * 4 + j4][wn] = b;
        }
    __syncthreads();
    if (tid < 128) {
        u64 a = shk[tid][0], b = shk[tid][1];
        atomicMin(&keys[m0 + tid], a < b ? a : b);
    }
}

// ---------------------------------------------------------------------------
// Gather chosen code (fp32 exact), update residual, accumulate
// sum(resid_new^2), reset keys for the next level.
// Round-9: float4-vectorized (16B/lane on rin/E/resid/latent/aux, G13);
// thread = 4 cols x 4 rows.  keys reset moved after __syncthreads (fixes a
// latent intra-block read/reset race).  lsum grouping changes -> loss scalar
// may differ in the last ulp (within harness tolerance; pipeline is bf16).
// rin = residual input (latent at level 0).
// ---------------------------------------------------------------------------
template<bool LAST>
__global__ __launch_bounds__(256) void vq_update_k(
    const float* __restrict__ rin,
    float* __restrict__ resid, u16* __restrict__ aux,   // aux = rbf or qbf
    const float* __restrict__ latent,
    const float* __restrict__ E,
    u64* __restrict__ keys, double* __restrict__ acc)
{
    __shared__ float red[4];
    const int tid  = threadIdx.x;
    const int base = blockIdx.x * 16;
    const int rl   = tid >> 6;          // 0..3: row sub-slot
    const int c4   = (tid & 63) * 4;    // col group (4 floats = 16B)
    float lsum = 0.f;
#pragma unroll
    for (int r = 0; r < 4; ++r) {
        const int row = base + r * 4 + rl;
        const int idx = (int)(keys[row] & 0xFFFFFFFFull);
        const float4 q = *(const float4*)&E[(size_t)idx * LAT + c4];
        const float4 x = *(const float4*)&rin[(size_t)row * LAT + c4];
        float4 v;
        v.x = x.x - q.x; v.y = x.y - q.y; v.z = x.z - q.z; v.w = x.w - q.w;
        if constexpr (LAST) {
            const float4 lt = *(const float4*)&latent[(size_t)row * LAT + c4];
            ushort4 o;
            o.x = f2bf(lt.x - v.x); o.y = f2bf(lt.y - v.y);
            o.z = f2bf(lt.z - v.z); o.w = f2bf(lt.w - v.w);
            *(ushort4*)&aux[(size_t)row * LAT + c4] = o;
        } else {
            *(float4*)&resid[(size_t)row * LAT + c4] = v;
            ushort4 o;
            o.x = f2bf(v.x); o.y = f2bf(v.y); o.z = f2bf(v.z); o.w = f2bf(v.w);
            *(ushort4*)&aux[(size_t)row * LAT + c4] = o;
        }
        lsum = fmaf(v.x, v.x, lsum);
        lsum = fmaf(v.y, v.y, lsum);
        lsum = fmaf(v.z, v.z, lsum);
        lsum = fmaf(v.w, v.w, lsum);
    }
#pragma unroll
    for (int off = 32; off >= 1; off >>= 1) lsum += __shfl_xor(lsum, off);
    if ((tid & 63) == 0) red[tid >> 6] = lsum;
    __syncthreads();
    if (!LAST && tid < 16) keys[base + tid] = ~0ull;   // after sync: race-free
    if (tid == 0) atomicAdd(acc, (double)(red[0] + red[1] + red[2] + red[3]));
}

__global__ void finalize_k(const double* __restrict__ acc, float* __restrict__ out) {
    double total = 1.5 * acc[0] / (double)((size_t)N_ROWS * LAT)
                 + 0.5 * acc[1] / (double)((size_t)N_ROWS * OBS);
    out[0] = (float)total;
}

// ---------------------------------------------------------------------------
extern "C" void kernel_launch(void* const* d_in, const int* in_sizes, int n_in,
                              void* d_out, int out_size, void* d_ws, size_t ws_size,
                              hipStream_t stream)
{
    const float* x      = (const float*)d_in[0];
    const float* cb     = (const float*)d_in[1];
    const float* enc_w1 = (const float*)d_in[2];
    const float* enc_b1 = (const float*)d_in[3];
    const float* ln_g   = (const float*)d_in[4];
    const float* ln_b   = (const float*)d_in[5];
    const float* enc_w2 = (const float*)d_in[6];
    const float* enc_b2 = (const float*)d_in[7];
    const float* dec_w1 = (const float*)d_in[8];
    const float* dec_b1 = (const float*)d_in[9];
    const float* dec_w2 = (const float*)d_in[10];
    const float* dec_b2 = (const float*)d_in[11];

    char* ws = (char*)d_ws;
    const size_t MB = 1ull << 20;
    u16* hbuf = (u16*)ws;                          // 0-64MB: h_bf then dh_bf
    u16* cbb  = (u16*)(ws + 64 * MB);              // -2E bf16, live all launch
    u16* rbf  = (u16*)(ws + 80 * MB);
    u16* qbf  = (u16*)(ws + 88 * MB);
    u16* xbf  = (u16*)(ws + 96 * MB);              // overlaps latent (dead by GEMM2)
    float* latent = (float*)(ws + 96 * MB);
    float* resid  = (float*)(ws + 112 * MB);
    u16* w1T  = (u16*)(ws + 128 * MB);   // [2048,1024]
    u16* w2T  = (u16*)(ws + 132 * MB);   // [256,2048]
    u16* wd1T = (u16*)(ws + 133 * MB);   // [2048,256]
    u16* wd2T = (u16*)(ws + 134 * MB);   // [1024,2048]
    float* enorm = (float*)(ws + 138 * MB);
    u64*   keys  = (u64*)(ws + 138 * MB + 131072);
    double* accs = (double*)(ws + 138 * MB + 262144);

    // fused: enorm + (-2E bf16) + keys/accs init
    enorm_k<<<HQ * VOCAB / 4, 256, 0, stream>>>(cb, enorm, cbb, keys, accs);

    // all weight transposes + x conversion in one launch
    prep_k<<<5120 + (int)((size_t)N_ROWS * OBS / 1024), 256, 0, stream>>>(
        enc_w1, w1T, enc_w2, w2T, dec_w1, wd1T, dec_w2, wd2T, x, xbf);

    // encoder: GEMM1 -> LN+ReLU -> GEMM2 (64-tile)
    mfma_gemm_k<0><<<dim3(N_ROWS / 128, HID / 128), 256, 0, stream>>>(
        xbf, w1T, enc_b1, hbuf, nullptr, nullptr, OBS, HID);
    ln_relu_bf_k<<<N_ROWS, 256, 0, stream>>>(hbuf, ln_g, ln_b);
    gemm2_k<<<dim3(N_ROWS / 64, LAT / 64), 256, 0, stream>>>(
        hbuf, w2T, enc_b2, latent, rbf);

    for (int l = 0; l < HQ; ++l) {
        dist_mfma_k<<<dim3(N_ROWS / 128, VOCAB / (64 * DNT)), 256, 0, stream>>>(
            rbf, cbb + (size_t)l * VOCAB * LAT, enorm + (size_t)l * VOCAB, keys);
        const float* rin = (l == 0) ? latent : resid;
        if (l < HQ - 1)
            vq_update_k<false><<<N_ROWS / 16, 256, 0, stream>>>(
                rin, resid, rbf, nullptr, cb + (size_t)l * VOCAB * LAT, keys, accs);
        else
            vq_update_k<true><<<N_ROWS / 16, 256, 0, stream>>>(
                rin, resid, qbf, latent, cb + (size_t)l * VOCAB * LAT, keys, accs);
    }

    // decoder GEMM3 -> GEMM4(+loss)
    mfma_gemm_k<1><<<dim3(N_ROWS / 128, HID / 128), 256, 0, stream>>>(
        qbf, wd1T, dec_b1, hbuf, nullptr, nullptr, LAT, HID);
    mfma_gemm_k<3><<<dim3(N_ROWS / 128, OBS / 128), 256, 0, stream>>>(
        hbuf, wd2T, dec_b2, nullptr, x, accs + 1, HID, OBS);

    finalize_k<<<1, 1, 0, stream>>>(accs, (float*)d_out);
}

// Round 11
// 726.082 us; speedup vs baseline: 1.0918x; 1.0918x over previous
//
#include <hip/hip_runtime.h>

#define N_ROWS 16384
#define OBS    1024
#define HID    2048
#define LAT    256
#define VOCAB  8192
#define HQ     4
#define LN_EPS 1e-5f

typedef unsigned short u16;
typedef unsigned long long u64;
typedef __bf16 bf16x8 __attribute__((ext_vector_type(8)));
typedef float  f32x4  __attribute__((ext_vector_type(4)));

static __device__ __forceinline__ unsigned int float_to_ordered(float f) {
    unsigned int u = __float_as_uint(f);
    return (u & 0x80000000u) ? ~u : (u | 0x80000000u);
}
// fp32 -> bf16 round-to-nearest-even
static __device__ __forceinline__ u16 f2bf(float f) {
    unsigned int u = __float_as_uint(f);
    unsigned int r = u + 0x7FFFu + ((u >> 16) & 1u);
    return (u16)(r >> 16);
}
static __device__ __forceinline__ float bf2f(u16 u) {
    return __uint_as_float((unsigned int)u << 16);
}

#define GL2LDS(gp, lp) __builtin_amdgcn_global_load_lds( \
    (const __attribute__((address_space(1))) void*)(gp), \
    (__attribute__((address_space(3))) void*)(lp), 16, 0, 0)

// ---------------------------------------------------------------------------
// bf16 MFMA GEMM, 128x128 tile, C = A @ B^T + bias. (verified rounds 3-6)
// EPI 0: store bf16 C.  1: relu + store bf16 C.  3: fused loss, no store.
// ---------------------------------------------------------------------------
template<int EPI>
__global__ __launch_bounds__(256, 4) void mfma_gemm_k(
    const u16* __restrict__ Abf, const u16* __restrict__ Bbf,
    const float* __restrict__ bias,
    u16* __restrict__ Cbf,
    const float* __restrict__ X, double* __restrict__ lacc,
    int K, int Nd)
{
    __shared__ u16 As[128 * 64];
    __shared__ u16 Bs[128 * 64];

    const int tid  = threadIdx.x;
    const int wv   = tid >> 6, lane = tid & 63;
    const int wm   = wv & 1,   wn   = wv >> 1;
    const int m_   = lane & 15, g   = lane >> 4;
    const int m0   = blockIdx.x * 128;
    const int n0   = blockIdx.y * 128;

    f32x4 acc[4][4];
#pragma unroll
    for (int i = 0; i < 4; ++i)
#pragma unroll
        for (int j = 0; j < 4; ++j)
            acc[i][j] = f32x4{0.f, 0.f, 0.f, 0.f};

    const u16* Ablk = Abf + (size_t)m0 * K;
    const u16* Bblk = Bbf + (size_t)n0 * K;

    for (int k0 = 0; k0 < K; k0 += 64) {
#pragma unroll
        for (int c = 0; c < 4; ++c) {
            const int ci = (wv * 4 + c) * 64 + lane;
            const int r  = ci >> 3;
            const int cc = ci & 7;
            const int kc = (cc ^ (r & 7)) << 3;
            GL2LDS(Ablk + (size_t)r * K + k0 + kc, As + (wv * 4 + c) * 512);
            GL2LDS(Bblk + (size_t)r * K + k0 + kc, Bs + (wv * 4 + c) * 512);
        }
        __syncthreads();
#pragma unroll
        for (int ks = 0; ks < 2; ++ks) {
            const int ccw = ks * 4 + g;
            const int sw  = (ccw ^ (m_ & 7)) << 3;
            bf16x8 af[4], bfr[4];
#pragma unroll
            for (int t = 0; t < 4; ++t) {
                af[t]  = *(const bf16x8*)&As[(wm * 64 + t * 16 + m_) * 64 + sw];
                bfr[t] = *(const bf16x8*)&Bs[(wn * 64 + t * 16 + m_) * 64 + sw];
            }
#pragma unroll
            for (int mi = 0; mi < 4; ++mi)
#pragma unroll
                for (int ni = 0; ni < 4; ++ni)
                    acc[mi][ni] = __builtin_amdgcn_mfma_f32_16x16x32_bf16(
                        af[mi], bfr[ni], acc[mi][ni], 0, 0, 0);
        }
        __syncthreads();
    }

    float bs[4];
#pragma unroll
    for (int ni = 0; ni < 4; ++ni) bs[ni] = bias[n0 + wn * 64 + ni * 16 + m_];

    if constexpr (EPI == 3) {
        float lsum = 0.f;
#pragma unroll
        for (int mi = 0; mi < 4; ++mi)
#pragma unroll
            for (int j = 0; j < 4; ++j) {
                const int row = m0 + wm * 64 + mi * 16 + g * 4 + j;
#pragma unroll
                for (int ni = 0; ni < 4; ++ni) {
                    const int col = n0 + wn * 64 + ni * 16 + m_;
                    float r = acc[mi][ni][j] + bs[ni] - X[(size_t)row * Nd + col];
                    lsum = fmaf(r, r, lsum);
                }
            }
#pragma unroll
        for (int off = 32; off >= 1; off >>= 1) lsum += __shfl_xor(lsum, off);
        __shared__ float red[4];
        if (lane == 0) red[wv] = lsum;
        __syncthreads();
        if (tid == 0)
            atomicAdd(lacc, (double)(red[0] + red[1] + red[2] + red[3]));
    } else {
#pragma unroll
        for (int mi = 0; mi < 4; ++mi)
#pragma unroll
            for (int j = 0; j < 4; ++j) {
                const int row = m0 + wm * 64 + mi * 16 + g * 4 + j;
#pragma unroll
                for (int ni = 0; ni < 4; ++ni) {
                    const int col = n0 + wn * 64 + ni * 16 + m_;
                    float v = acc[mi][ni][j] + bs[ni];
                    if constexpr (EPI == 1) v = fmaxf(v, 0.f);
                    Cbf[(size_t)row * Nd + col] = f2bf(v);
                }
            }
    }
}

// ---------------------------------------------------------------------------
// GEMM2 dedicated kernel: 64x64 tile.  latent = h @ w2T^T + b2.
// (resid store dropped round-8; vq level-0 reads latent.)
// ---------------------------------------------------------------------------
__global__ __launch_bounds__(256, 4) void gemm2_k(
    const u16* __restrict__ Abf, const u16* __restrict__ Bbf,
    const float* __restrict__ bias,
    float* __restrict__ lat, u16* __restrict__ rbf)
{
    __shared__ u16 As[64 * 64];
    __shared__ u16 Bs[64 * 64];

    const int tid = threadIdx.x;
    const int wv  = tid >> 6, lane = tid & 63;
    const int wm  = wv & 1,   wn   = wv >> 1;
    const int m_  = lane & 15, g   = lane >> 4;
    const int m0  = blockIdx.x * 64;
    const int n0  = blockIdx.y * 64;

    f32x4 acc[2][2];
#pragma unroll
    for (int i = 0; i < 2; ++i)
#pragma unroll
        for (int j = 0; j < 2; ++j)
            acc[i][j] = f32x4{0.f, 0.f, 0.f, 0.f};

    const u16* Ablk = Abf + (size_t)m0 * HID;
    const u16* Bblk = Bbf + (size_t)n0 * HID;

    for (int k0 = 0; k0 < HID; k0 += 64) {
#pragma unroll
        for (int c = 0; c < 2; ++c) {
            const int ci = (wv * 2 + c) * 64 + lane;
            const int r  = ci >> 3;
            const int cc = ci & 7;
            const int kc = (cc ^ (r & 7)) << 3;
            GL2LDS(Ablk + (size_t)r * HID + k0 + kc, As + (wv * 2 + c) * 512);
            GL2LDS(Bblk + (size_t)r * HID + k0 + kc, Bs + (wv * 2 + c) * 512);
        }
        __syncthreads();
#pragma unroll
        for (int ks = 0; ks < 2; ++ks) {
            const int ccw = ks * 4 + g;
            const int sw  = (ccw ^ (m_ & 7)) << 3;
            bf16x8 af[2], bfr[2];
#pragma unroll
            for (int t = 0; t < 2; ++t) {
                af[t]  = *(const bf16x8*)&As[(wm * 32 + t * 16 + m_) * 64 + sw];
                bfr[t] = *(const bf16x8*)&Bs[(wn * 32 + t * 16 + m_) * 64 + sw];
            }
#pragma unroll
            for (int mi = 0; mi < 2; ++mi)
#pragma unroll
                for (int ni = 0; ni < 2; ++ni)
                    acc[mi][ni] = __builtin_amdgcn_mfma_f32_16x16x32_bf16(
                        af[mi], bfr[ni], acc[mi][ni], 0, 0, 0);
        }
        __syncthreads();
    }

#pragma unroll
    for (int mi = 0; mi < 2; ++mi)
#pragma unroll
        for (int j = 0; j < 4; ++j) {
            const int row = m0 + wm * 32 + mi * 16 + g * 4 + j;
#pragma unroll
            for (int ni = 0; ni < 2; ++ni) {
                const int col = n0 + wn * 32 + ni * 16 + m_;
                float v = acc[mi][ni][j] + bias[col];
                lat[(size_t)row * LAT + col] = v;
                rbf[(size_t)row * LAT + col] = f2bf(v);
            }
        }
}

// ---------------------------------------------------------------------------
// Prep kernel: 4 weight transposes (blocks 0..5119) + x fp32->bf16
// (blocks 5120..21503) in ONE launch.
// ---------------------------------------------------------------------------
__global__ __launch_bounds__(256) void prep_k(
    const float* __restrict__ W0, u16* __restrict__ T0,   // enc_w1 1024x2048
    const float* __restrict__ W1, u16* __restrict__ T1,   // enc_w2 2048x256
    const float* __restrict__ W2, u16* __restrict__ T2,   // dec_w1 256x2048
    const float* __restrict__ W3, u16* __restrict__ T3,   // dec_w2 2048x1024
    const float* __restrict__ x, u16* __restrict__ xbf)
{
    __shared__ u16 t[32][33];
    const int bid = blockIdx.x;
    if (bid >= 5120) {   // f2bf path
        size_t i = ((size_t)(bid - 5120) * 256 + threadIdx.x) * 4;
        float4 v = *(const float4*)(x + i);
        ushort4 o;
        o.x = f2bf(v.x); o.y = f2bf(v.y); o.z = f2bf(v.z); o.w = f2bf(v.w);
        *(ushort4*)(xbf + i) = o;
        return;
    }
    const float* W; u16* T; int K, N, r;
    if (bid < 2048)      { W = W0; T = T0; K = OBS; N = HID; r = bid; }
    else if (bid < 2560) { W = W1; T = T1; K = HID; N = LAT; r = bid - 2048; }
    else if (bid < 3072) { W = W2; T = T2; K = LAT; N = HID; r = bid - 2560; }
    else                 { W = W3; T = T3; K = HID; N = OBS; r = bid - 3072; }
    const int nb = N >> 5;
    const int n0 = (r % nb) * 32, k0 = (r / nb) * 32;
    const int lx = threadIdx.x & 31, ly = threadIdx.x >> 5;
#pragma unroll
    for (int i = 0; i < 4; ++i)
        t[ly + 8 * i][lx] = f2bf(W[(size_t)(k0 + ly + 8 * i) * N + n0 + lx]);
    __syncthreads();
#pragma unroll
    for (int i = 0; i < 4; ++i)
        T[(size_t)(n0 + ly + 8 * i) * K + k0 + lx] = t[lx][ly + 8 * i];
}

// ---------------------------------------------------------------------------
// LayerNorm + ReLU in place on bf16 h (fp32 math), one block per row of 2048.
// ---------------------------------------------------------------------------
__device__ __forceinline__ float block_reduce_bcast(float v, float* scratch) {
#pragma unroll
    for (int off = 32; off >= 1; off >>= 1) v += __shfl_xor(v, off);
    const int tid = threadIdx.x;
    __syncthreads();
    if ((tid & 63) == 0) scratch[tid >> 6] = v;
    __syncthreads();
    return scratch[0] + scratch[1] + scratch[2] + scratch[3];
}

__global__ __launch_bounds__(256) void ln_relu_bf_k(
    u16* __restrict__ h, const float* __restrict__ g, const float* __restrict__ b)
{
    __shared__ float scratch[4];
    const int tid = threadIdx.x;
    u16* hp = h + (size_t)blockIdx.x * HID + tid * 8;

    ushort4 r0 = *(const ushort4*)hp;
    ushort4 r1 = *(const ushort4*)(hp + 4);
    float v[8] = {bf2f(r0.x), bf2f(r0.y), bf2f(r0.z), bf2f(r0.w),
                  bf2f(r1.x), bf2f(r1.y), bf2f(r1.z), bf2f(r1.w)};

    float s = 0.f;
#pragma unroll
    for (int e = 0; e < 8; ++e) s += v[e];
    const float mu = block_reduce_bcast(s, scratch) * (1.f / HID);

    float vs = 0.f;
#pragma unroll
    for (int e = 0; e < 8; ++e) { float d = v[e] - mu; vs = fmaf(d, d, vs); }
    const float var = block_reduce_bcast(vs, scratch) * (1.f / HID);
    const float rs = rsqrtf(var + LN_EPS);

    ushort4 o0, o1;
#pragma unroll
    for (int e = 0; e < 8; ++e) {
        const int col = tid * 8 + e;
        float w = (v[e] - mu) * rs * g[col] + b[col];
        w = fmaxf(w, 0.f);
        u16 bb = f2bf(w);
        if (e < 4) ((u16*)&o0)[e] = bb; else ((u16*)&o1)[e - 4] = bb;
    }
    *(ushort4*)hp = o0;
    *(ushort4*)(hp + 4) = o1;
}

// ---------------------------------------------------------------------------
// Fused codebook pass: exact fp32 norms + bf16(-2E) copy + keys/accs init.
// ---------------------------------------------------------------------------
__global__ __launch_bounds__(256) void enorm_k(
    const float* __restrict__ cb, float* __restrict__ enorm,
    u16* __restrict__ cbb, u64* __restrict__ keys, double* __restrict__ accs)
{
    if (blockIdx.x < 64) keys[blockIdx.x * 256 + threadIdx.x] = ~0ull;
    if (blockIdx.x == 64 && threadIdx.x < 2) accs[threadIdx.x] = 0.0;
    const int row  = blockIdx.x * 4 + (threadIdx.x >> 6);
    const int lane = threadIdx.x & 63;
    const size_t off = (size_t)row * LAT + lane * 4;
    float4 v = *(const float4*)(cb + off);
    ushort4 o;
    o.x = f2bf(-2.f * v.x); o.y = f2bf(-2.f * v.y);
    o.z = f2bf(-2.f * v.z); o.w = f2bf(-2.f * v.w);
    *(ushort4*)(cbb + off) = o;
    float s = v.x * v.x + v.y * v.y + v.z * v.z + v.w * v.w;
#pragma unroll
    for (int off2 = 32; off2 >= 1; off2 >>= 1) s += __shfl_xor(s, off2);
    if (lane == 0) enorm[row] = s;
}

// ---------------------------------------------------------------------------
// Distance + argmin, round-11 (= round-10 resubmit + #pragma unroll 1 on the
// phase loop): M=256 per block (8 waves, 512 threads).  Mechanism: the
// 2-block/CU M=128 version jointly stages 64KB/phase vs a ~620-cyc/SIMD MFMA
// window -- staging can't hide, each barrier exposes the difference.
// Doubling rows/block makes the SAME 32KB B-stage feed 2x the MFMAs
// (staged-bytes/MFMA halves, barriers/work halve).  All data paths (stage
// swizzle, read swizzle, MFMA order, fold, sync) byte-identical to the
// twice-proven r2/r5 kernel; only wave-role decode (wm=wv>>1), m0 scale,
// grid.x, and epilogue extent change.  Audit (r10 post-mortem): no barrier
// divergence, bounds verified, LDS 69632B/block (1 block/CU at 8 waves),
// VGPR ~210 <= 256 cap -- no hang mechanism; r10 container failure matches
// the r3 infra-flake signature (r4 resubmit passed).
// ---------------------------------------------------------------------------
#define DNT 16

__global__ __launch_bounds__(512, 2) void dist_mfma_k(
    const u16* __restrict__ Abf, const u16* __restrict__ Bneg2,
    const float* __restrict__ enorm, u64* __restrict__ keys)
{
    __shared__ u16 Bs[2][64 * 256];   // 2 x 32 KB double buffer
    __shared__ u64 shk[256][2];

    const int tid  = threadIdx.x;
    const int wv   = tid >> 6, lane = tid & 63;
    const int wm   = wv >> 1,  wn   = wv & 1;   // 4 row-groups x 2 col-groups
    const int m_   = lane & 15, g   = lane >> 4;
    const int m0   = blockIdx.x * 256;
    const int c0   = blockIdx.y * (64 * DNT);

    // ---- A fragments: direct global -> registers, K=256 resident ----------
    // wave owns 64 rows: wm*64 + mi*16 + m_
    bf16x8 af[4][8];
    {
        const u16* Ablk = Abf + (size_t)m0 * LAT;
#pragma unroll
        for (int mi = 0; mi < 4; ++mi) {
            const u16* rp = Ablk + (size_t)(wm * 64 + mi * 16 + m_) * LAT + g * 8;
#pragma unroll
            for (int kk = 0; kk < 8; ++kk)
                af[mi][kk] = *(const bf16x8*)(rp + kk * 32);
        }
    }

    float bestf[4][4];
    int   besti[4][4];
#pragma unroll
    for (int mi = 0; mi < 4; ++mi)
#pragma unroll
        for (int j4 = 0; j4 < 4; ++j4) {
            bestf[mi][j4] = __int_as_float(0x7f800000);  // +inf
            besti[mi][j4] = 0;
        }

    const u16* Bbase = Bneg2 + (size_t)c0 * LAT;

    // stage B sub-tile j (64 vocab rows x 256 K): 4 GL2LDS per thread,
    // same chunk->LDS mapping as the proven 256-thread version.
    auto stageB = [&](int j, int buf) {
#pragma unroll
        for (int t = 0; t < 4; ++t) {
            const int idx = wv * 64 + lane;      // 0..511
            const int r   = idx >> 3;            // 0..63
            const int cc  = idx & 7;
            const int kc  = (cc ^ (r & 7)) << 3;
            GL2LDS(Bbase + (size_t)(j * 64 + r) * LAT + t * 64 + kc,
                   &Bs[buf][t * 4096 + wv * 512]);
        }
    };

    stageB(0, 0);

    // enorm prefetch, one sub-tile ahead (wave's 32-col slice)
    const int ecol = wn * 32 + m_;
    float enA = enorm[c0 + ecol];
    float enB = enorm[c0 + ecol + 16];

    __syncthreads();

#pragma unroll 1
    for (int j = 0; j < DNT; ++j) {
        const int cur = j & 1;
        if (j + 1 < DNT) stageB(j + 1, cur ^ 1);

        float enA_n = 0.f, enB_n = 0.f;
        if (j + 1 < DNT) {
            enA_n = enorm[c0 + (j + 1) * 64 + ecol];
            enB_n = enorm[c0 + (j + 1) * 64 + ecol + 16];
        }

        const int bc = c0 + j * 64 + ecol;
        f32x4 acc[4][2];
#pragma unroll
        for (int mi = 0; mi < 4; ++mi) {
            acc[mi][0] = f32x4{enA, enA, enA, enA};
            acc[mi][1] = f32x4{enB, enB, enB, enB};
        }

        const u16* bsc = &Bs[cur][0];
#pragma unroll
        for (int kc_ = 0; kc_ < 4; ++kc_)
#pragma unroll
            for (int ks = 0; ks < 2; ++ks) {
                const int ccw = ks * 4 + g;
                const int sw  = (ccw ^ (m_ & 7)) << 3;
                bf16x8 b0 = *(const bf16x8*)
                    &bsc[kc_ * 4096 + (wn * 32 + m_) * 64 + sw];
                bf16x8 b1 = *(const bf16x8*)
                    &bsc[kc_ * 4096 + (wn * 32 + 16 + m_) * 64 + sw];
                const int kk = kc_ * 2 + ks;
#pragma unroll
                for (int mi = 0; mi < 4; ++mi) {
                    acc[mi][0] = __builtin_amdgcn_mfma_f32_16x16x32_bf16(
                        af[mi][kk], b0, acc[mi][0], 0, 0, 0);
                    acc[mi][1] = __builtin_amdgcn_mfma_f32_16x16x32_bf16(
                        af[mi][kk], b1, acc[mi][1], 0, 0, 0);
                }
            }

        // cheap fold: float compare + index select, ascending column order
#pragma unroll
        for (int mi = 0; mi < 4; ++mi)
#pragma unroll
            for (int j4 = 0; j4 < 4; ++j4) {
                const float s0 = acc[mi][0][j4];
                const float s1 = acc[mi][1][j4];
                if (s0 < bestf[mi][j4]) { bestf[mi][j4] = s0; besti[mi][j4] = bc; }
                if (s1 < bestf[mi][j4]) { bestf[mi][j4] = s1; besti[mi][j4] = bc + 16; }
            }

        enA = enA_n; enB = enB_n;
        __syncthreads();   // Bs[cur^1] staged complete; Bs[cur] reads done
    }

    // ---- epilogue: pack once, reduce over the 16 m_ lanes, merge wn halves
#pragma unroll
    for (int mi = 0; mi < 4; ++mi)
#pragma unroll
        for (int j4 = 0; j4 < 4; ++j4) {
            u64 b = ((u64)float_to_ordered(bestf[mi][j4]) << 32)
                  | (unsigned)besti[mi][j4];
#pragma unroll
            for (int mask = 1; mask <= 8; mask <<= 1) {
                u64 o = __shfl_xor(b, mask);
                b = o < b ? o : b;
            }
            if (m_ == 0) shk[wm * 64 + mi * 16 + g * 4 + j4][wn] = b;
        }
    __syncthreads();
    if (tid < 256) {
        u64 a = shk[tid][0], b = shk[tid][1];
        atomicMin(&keys[m0 + tid], a < b ? a : b);
    }
}

// ---------------------------------------------------------------------------
// Gather chosen code (fp32 exact), update residual, accumulate
// sum(resid_new^2), reset keys for the next level.  float4-vectorized.
// rin = residual input (latent at level 0).
// ---------------------------------------------------------------------------
template<bool LAST>
__global__ __launch_bounds__(256) void vq_update_k(
    const float* __restrict__ rin,
    float* __restrict__ resid, u16* __restrict__ aux,   // aux = rbf or qbf
    const float* __restrict__ latent,
    const float* __restrict__ E,
    u64* __restrict__ keys, double* __restrict__ acc)
{
    __shared__ float red[4];
    const int tid  = threadIdx.x;
    const int base = blockIdx.x * 16;
    const int rl   = tid >> 6;          // 0..3: row sub-slot
    const int c4   = (tid & 63) * 4;    // col group (4 floats = 16B)
    float lsum = 0.f;
#pragma unroll
    for (int r = 0; r < 4; ++r) {
        const int row = base + r * 4 + rl;
        const int idx = (int)(keys[row] & 0xFFFFFFFFull);
        const float4 q = *(const float4*)&E[(size_t)idx * LAT + c4];
        const float4 x = *(const float4*)&rin[(size_t)row * LAT + c4];
        float4 v;
        v.x = x.x - q.x; v.y = x.y - q.y; v.z = x.z - q.z; v.w = x.w - q.w;
        if constexpr (LAST) {
            const float4 lt = *(const float4*)&latent[(size_t)row * LAT + c4];
            ushort4 o;
            o.x = f2bf(lt.x - v.x); o.y = f2bf(lt.y - v.y);
            o.z = f2bf(lt.z - v.z); o.w = f2bf(lt.w - v.w);
            *(ushort4*)&aux[(size_t)row * LAT + c4] = o;
        } else {
            *(float4*)&resid[(size_t)row * LAT + c4] = v;
            ushort4 o;
            o.x = f2bf(v.x); o.y = f2bf(v.y); o.z = f2bf(v.z); o.w = f2bf(v.w);
            *(ushort4*)&aux[(size_t)row * LAT + c4] = o;
        }
        lsum = fmaf(v.x, v.x, lsum);
        lsum = fmaf(v.y, v.y, lsum);
        lsum = fmaf(v.z, v.z, lsum);
        lsum = fmaf(v.w, v.w, lsum);
    }
#pragma unroll
    for (int off = 32; off >= 1; off >>= 1) lsum += __shfl_xor(lsum, off);
    if ((tid & 63) == 0) red[tid >> 6] = lsum;
    __syncthreads();
    if (!LAST && tid < 16) keys[base + tid] = ~0ull;   // after sync: race-free
    if (tid == 0) atomicAdd(acc, (double)(red[0] + red[1] + red[2] + red[3]));
}

__global__ void finalize_k(const double* __restrict__ acc, float* __restrict__ out) {
    double total = 1.5 * acc[0] / (double)((size_t)N_ROWS * LAT)
                 + 0.5 * acc[1] / (double)((size_t)N_ROWS * OBS);
    out[0] = (float)total;
}

// ---------------------------------------------------------------------------
extern "C" void kernel_launch(void* const* d_in, const int* in_sizes, int n_in,
                              void* d_out, int out_size, void* d_ws, size_t ws_size,
                              hipStream_t stream)
{
    const float* x      = (const float*)d_in[0];
    const float* cb     = (const float*)d_in[1];
    const float* enc_w1 = (const float*)d_in[2];
    const float* enc_b1 = (const float*)d_in[3];
    const float* ln_g   = (const float*)d_in[4];
    const float* ln_b   = (const float*)d_in[5];
    const float* enc_w2 = (const float*)d_in[6];
    const float* enc_b2 = (const float*)d_in[7];
    const float* dec_w1 = (const float*)d_in[8];
    const float* dec_b1 = (const float*)d_in[9];
    const float* dec_w2 = (const float*)d_in[10];
    const float* dec_b2 = (const float*)d_in[11];

    char* ws = (char*)d_ws;
    const size_t MB = 1ull << 20;
    u16* hbuf = (u16*)ws;                          // 0-64MB: h_bf then dh_bf
    u16* cbb  = (u16*)(ws + 64 * MB);              // -2E bf16, live all launch
    u16* rbf  = (u16*)(ws + 80 * MB);
    u16* qbf  = (u16*)(ws + 88 * MB);
    u16* xbf  = (u16*)(ws + 96 * MB);              // overlaps latent (dead by GEMM2)
    float* latent = (float*)(ws + 96 * MB);
    float* resid  = (float*)(ws + 112 * MB);
    u16* w1T  = (u16*)(ws + 128 * MB);   // [2048,1024]
    u16* w2T  = (u16*)(ws + 132 * MB);   // [256,2048]
    u16* wd1T = (u16*)(ws + 133 * MB);   // [2048,256]
    u16* wd2T = (u16*)(ws + 134 * MB);   // [1024,2048]
    float* enorm = (float*)(ws + 138 * MB);
    u64*   keys  = (u64*)(ws + 138 * MB + 131072);
    double* accs = (double*)(ws + 138 * MB + 262144);

    // fused: enorm + (-2E bf16) + keys/accs init
    enorm_k<<<HQ * VOCAB / 4, 256, 0, stream>>>(cb, enorm, cbb, keys, accs);

    // all weight transposes + x conversion in one launch
    prep_k<<<5120 + (int)((size_t)N_ROWS * OBS / 1024), 256, 0, stream>>>(
        enc_w1, w1T, enc_w2, w2T, dec_w1, wd1T, dec_w2, wd2T, x, xbf);

    // encoder: GEMM1 -> LN+ReLU -> GEMM2 (64-tile)
    mfma_gemm_k<0><<<dim3(N_ROWS / 128, HID / 128), 256, 0, stream>>>(
        xbf, w1T, enc_b1, hbuf, nullptr, nullptr, OBS, HID);
    ln_relu_bf_k<<<N_ROWS, 256, 0, stream>>>(hbuf, ln_g, ln_b);
    gemm2_k<<<dim3(N_ROWS / 64, LAT / 64), 256, 0, stream>>>(
        hbuf, w2T, enc_b2, latent, rbf);

    for (int l = 0; l < HQ; ++l) {
        dist_mfma_k<<<dim3(N_ROWS / 256, VOCAB / (64 * DNT)), 512, 0, stream>>>(
            rbf, cbb + (size_t)l * VOCAB * LAT, enorm + (size_t)l * VOCAB, keys);
        const float* rin = (l == 0) ? latent : resid;
        if (l < HQ - 1)
            vq_update_k<false><<<N_ROWS / 16, 256, 0, stream>>>(
                rin, resid, rbf, nullptr, cb + (size_t)l * VOCAB * LAT, keys, accs);
        else
            vq_update_k<true><<<N_ROWS / 16, 256, 0, stream>>>(
                rin, resid, qbf, latent, cb + (size_t)l * VOCAB * LAT, keys, accs);
    }

    // decoder GEMM3 -> GEMM4(+loss)
    mfma_gemm_k<1><<<dim3(N_ROWS / 128, HID / 128), 256, 0, stream>>>(
        qbf, wd1T, dec_b1, hbuf, nullptr, nullptr, LAT, HID);
    mfma_gemm_k<3><<<dim3(N_ROWS / 128, OBS / 128), 256, 0, stream>>>(
        hbuf, wd2T, dec_b2, nullptr, x, accs + 1, HID, OBS);

    finalize_k<<<1, 1, 0, stream>>>(accs, (float*)d_out);
}